// Round 1
// 261.513 us; speedup vs baseline: 1.0338x; 1.0338x over previous
//
#include <hip/hip_runtime.h>
#include <stdint.h>

// ModulatedConv2d: B=8, C=512, O=512, K=3, WDIM=512, H=W=64
// Round-6 restructure: weight factorization W[b,o,c,t] = bw[o,c,t]*s[b,c]*D[b,o].
//   s folded into activation transpose (k_prep), D folded into conv epilogue.
//   A-operand of the implicit GEMM is now batch-independent bf16(bw): 4.7 MB
//   (was 37.7 MB per-batch wmod). k_fw shrinks to demod-reduce + bf16 convert.

#define MOD_SCALE  0.044194173824159216f   // 1/sqrt(512)
#define CONV_SCALE 0.014731391274719739f   // 1/sqrt(4608)

typedef __attribute__((ext_vector_type(4))) float f32x4;
typedef __attribute__((ext_vector_type(8))) short bf16x8;

__device__ inline unsigned short f2bf(float f) {   // round-to-nearest-even
  uint32_t u = __float_as_uint(f);
  uint32_t r = (u + 0x7fffu + ((u >> 16) & 1u)) >> 16;
  return (unsigned short)r;
}

__device__ inline void gload_lds16(const void* g, void* l) {
  __builtin_amdgcn_global_load_lds(
      (const __attribute__((address_space(1))) void*)g,
      (__attribute__((address_space(3))) void*)l, 16, 0, 0);
}

// ---------- style: s[b][c] = w[b].modw[c]*MOD_SCALE + modb[c] + 1 ----------
// 64 blocks (8 c-blocks x 8 batches), 4-way split-K per c.
__global__ __launch_bounds__(256) void k_style(const float* __restrict__ w,
                                               const float* __restrict__ modw,
                                               const float* __restrict__ modb,
                                               float* __restrict__ s_out) {
  __shared__ float red[256];
  const int tid = threadIdx.x;
  const int sb = blockIdx.x;
  const int cb = sb & 7, b = sb >> 3;
  const int cl = tid >> 2, qq = tid & 3;
  const int c = (cb << 6) + cl;
  const float4* wd = (const float4*)(w + (b << 9) + (qq << 7));
  const float4* md = (const float4*)(modw + ((size_t)c << 9) + (qq << 7));
  float acc = 0.f;
#pragma unroll
  for (int i = 0; i < 32; ++i) {
    float4 a = wd[i], m = md[i];
    acc += a.x * m.x + a.y * m.y + a.z * m.z + a.w * m.w;
  }
  red[tid] = acc;
  __syncthreads();
  if (tid < 64) {
    float v = red[tid * 4] + red[tid * 4 + 1] + red[tid * 4 + 2] + red[tid * 4 + 3];
    int cc = (cb << 6) + tid;
    s_out[(b << 9) + cc] = v * MOD_SCALE + modb[cc] + 1.0f;
  }
}

// ---------- prep: xpad[b][py][px][c] = bf16(x[b][c][py-1][px-1] * s[b][c]) ----------
// blk < 4096: transpose+modulate; blk < 6176: zero pad border.
__global__ __launch_bounds__(256) void k_prep(const float* __restrict__ x,
                                              const float* __restrict__ s,
                                              unsigned short* __restrict__ xp) {
  __shared__ unsigned short smem[64 * 65];
  const int blk = blockIdx.x;
  const int tid = threadIdx.x;
  if (blk < 4096) {
    const int b = blk >> 9, r = blk & 511;
    const int c0 = ((r >> 6) << 6), p0 = ((r & 63) << 6);
    {
      const int pi = tid & 63, ci0 = tid >> 6;
      const float* src = x + (size_t)((b << 9) + c0 + ci0) * 4096 + p0 + pi;
      const float* sv = s + (b << 9) + c0 + ci0;   // wave-uniform scale
#pragma unroll
      for (int it = 0; it < 16; ++it)
        smem[(ci0 + (it << 2)) * 65 + pi] =
            f2bf(src[(size_t)(it << 2) * 4096] * sv[it << 2]);
    }
    __syncthreads();
    {
      const int cq = tid & 31, pq = tid >> 5;   // c-pair, pixel-in-group
#pragma unroll
      for (int it = 0; it < 8; ++it) {
        const int p = pq + (it << 3);
        const int gp = p0 + p;
        const int py = (gp >> 6) + 1, px = (gp & 63) + 1;
        uint32_t v = (uint32_t)smem[(cq << 1) * 65 + p] |
                     ((uint32_t)smem[((cq << 1) + 1) * 65 + p] << 16);
        ((uint32_t*)(xp + ((size_t)b * 4356 + py * 66 + px) * 512 + c0))[cq] = v;
      }
    }
  } else {
    // ---- zero pad border (260 segments x 8 batches) ----
    const int q = blk - 4096;
    const int b = q / 260, p = q - b * 260;
    int py, px;
    if (p < 66)       { py = 0;       px = p; }
    else if (p < 132) { py = 65;      px = p - 66; }
    else if (p < 196) { py = p - 131; px = 0; }
    else              { py = p - 195; px = 65; }
    uint32_t* dst = (uint32_t*)(xp + ((size_t)b * 4356 + py * 66 + px) * 512);
    dst[tid] = 0u;
  }
}

// ---------- fused demod + weight convert: one block per o ----------
// D[b][o] = rsqrt( (sum_c wsq[o][c]*s[b][c]^2) / 4608 ) * CONV_SCALE
// awT[o][tap][c] = bf16(bw[o][c][tap])   (batch-independent!)
__global__ __launch_bounds__(256) void k_fwd(const float* __restrict__ bw,
                                             const float* __restrict__ s,
                                             unsigned short* __restrict__ awT,
                                             float* __restrict__ d_out) {
  __shared__ float lw[4608];   // bw row, [c][tap]
  __shared__ float ls[4096];   // s, [b][c]
  __shared__ float red[32];
  const int tid = threadIdx.x;
  const int o = blockIdx.x;
  {
    const float4* src = (const float4*)(bw + (size_t)o * 4608);
    float4* dst = (float4*)lw;
#pragma unroll
    for (int i = 0; i < 4; ++i) dst[tid + (i << 8)] = src[tid + (i << 8)];
    if (tid < 128) dst[tid + 1024] = src[tid + 1024];
  }
  {
    const float4* src = (const float4*)s;
    float4* dst = (float4*)ls;
#pragma unroll
    for (int i = 0; i < 4; ++i) dst[tid + (i << 8)] = src[tid + (i << 8)];
  }
  __syncthreads();
  const int c0 = tid << 1;
  const int base = c0 * 9;
  float wq0 = 0.f, wq1 = 0.f;
#pragma unroll
  for (int j = 0; j < 9; ++j) {
    float a = lw[base + j];      wq0 += a * a;
    float b2 = lw[base + 9 + j]; wq1 += b2 * b2;
  }
  const int lane = tid & 63, wv = tid >> 6;
#pragma unroll
  for (int b = 0; b < 8; ++b) {
    float s0 = ls[(b << 9) + c0], s1 = ls[(b << 9) + c0 + 1];
    float v = wq0 * s0 * s0 + wq1 * s1 * s1;
#pragma unroll
    for (int off = 32; off > 0; off >>= 1) v += __shfl_down(v, off, 64);
    if (lane == 0) red[(b << 2) + wv] = v;
  }
  __syncthreads();
  if (tid < 8) {
    float a = red[tid << 2] + red[(tid << 2) + 1] + red[(tid << 2) + 2] + red[(tid << 2) + 3];
    d_out[(tid << 9) + o] = rsqrtf(a * (1.0f / 4608.0f)) * CONV_SCALE;
  }
  // bf16 convert of the raw base weight (once, no per-batch loop)
  uint32_t* dst = (uint32_t*)(awT + (size_t)o * 4608);
#pragma unroll
  for (int j = 0; j < 9; ++j)
    dst[(j << 8) + tid] = (uint32_t)f2bf(lw[base + j]) |
                          ((uint32_t)f2bf(lw[base + 9 + j]) << 16);
}

// ---------- main conv: 128x128 tile, BK=64, B-halo shared across kx taps ----------
// A-operand is the batch-independent awT; D[b][o] applied in fp32 epilogue.
__global__ __launch_bounds__(256, 2) void k_conv(const unsigned short* __restrict__ awT,
                                                 const unsigned short* __restrict__ xpad,
                                                 const float* __restrict__ dmod,
                                                 float* __restrict__ out) {
  __shared__ alignas(16) unsigned short As[3 * 8192];  // 48 KB
  __shared__ alignas(16) unsigned short Bs[8448];      // 16.5 KB
  const int tid = threadIdx.x;
  const int b  = blockIdx.z;
  const int m0 = blockIdx.y << 7;
  const int n0 = blockIdx.x << 7;
  const int y0 = n0 >> 6;

  const int srow = tid >> 3;                         // 0..31
  const int schk = ((tid & 7) - (srow & 7)) & 7;     // swizzled logical chunk
  const int scol = schk << 3;

  const unsigned short* A0 = awT + (size_t)(m0 + srow) * 4608 + scol;
  const size_t bx = (size_t)b * (66 * 66 * 512);

  const int lane = tid & 63;
  const int wv   = tid >> 6;
  const int moff = (wv >> 1) << 6;
  const int noff = (wv & 1) << 6;
  const int noffp = noff ? 66 : 0;   // halo-strip row base for this wave
  const int lm   = lane & 15;
  const int g4   = lane >> 4;

  // A reader bases (chunk const across i since 16i = 0 mod 8); +kx*8192 selects panel
  const unsigned short* ardA[2];
#pragma unroll
  for (int h = 0; h < 2; ++h)
    ardA[h] = As + (moff + lm) * 64 + ((((h << 2) + g4) + moff + lm) & 7) * 8;
  // B reader bases per (kx,h): row = noffp + lm + kx (+16j)
  const unsigned short* ardB[3][2];
#pragma unroll
  for (int kx = 0; kx < 3; ++kx) {
    const int rb = noffp + lm + kx;
#pragma unroll
    for (int h = 0; h < 2; ++h)
      ardB[kx][h] = Bs + rb * 64 + ((((h << 2) + g4) + rb) & 7) * 8;
  }

  f32x4 acc[4][4];
#pragma unroll
  for (int i = 0; i < 4; ++i)
#pragma unroll
    for (int j = 0; j < 4; ++j) acc[i][j] = (f32x4){0.f, 0.f, 0.f, 0.f};

#pragma unroll 1
  for (int ky = 0; ky < 3; ++ky) {
    const unsigned short* Bp0 = xpad + bx + (size_t)((y0 + ky) * 66 + srow) * 512 + scol;
#pragma unroll 1
    for (int kb = 0; kb < 8; ++kb) {
      const int kcol = kb << 6;
      // stage 3 A tap-panels
#pragma unroll
      for (int kx = 0; kx < 3; ++kx) {
        const unsigned short* Ap = A0 + ((ky * 3 + kx) << 9) + kcol;
#pragma unroll
        for (int g = 0; g < 4; ++g)
          gload_lds16(Ap + g * (32 * 4608), As + ((kx << 13) + (((g << 8) + tid) << 3)));
      }
      // stage B halo strip: 132 rows (linear: pixel offset = (y0+ky)*66 + hr)
      const unsigned short* Bp = Bp0 + kcol;
#pragma unroll
      for (int g = 0; g < 4; ++g)
        gload_lds16(Bp + g * (32 * 512), Bs + (((g << 8) + tid) << 3));
      if (tid < 32) gload_lds16(Bp + 128 * 512, Bs + 8192 + tid * 8);
      __syncthreads();
#pragma unroll
      for (int kx = 0; kx < 3; ++kx) {
#pragma unroll
        for (int h = 0; h < 2; ++h) {
          bf16x8 af[4], bf[4];
          const unsigned short* pa = ardA[h] + (kx << 13);
          const unsigned short* pb = ardB[kx][h];
#pragma unroll
          for (int i = 0; i < 4; ++i) af[i] = *(const bf16x8*)(pa + (i << 10));
#pragma unroll
          for (int j = 0; j < 4; ++j) bf[j] = *(const bf16x8*)(pb + (j << 10));
#pragma unroll
          for (int i = 0; i < 4; ++i)
#pragma unroll
            for (int j = 0; j < 4; ++j)
              acc[i][j] = __builtin_amdgcn_mfma_f32_16x16x32_bf16(af[i], bf[j], acc[i][j], 0, 0, 0);
        }
      }
      __syncthreads();
    }
  }

  // epilogue: D layout col=lane&15 (pixel), row=(lane>>4)*4+reg (o); apply D[b][o]
  const float* dB = dmod + (b << 9) + m0 + moff;
  float* op = out + (size_t)((b << 9) + m0 + moff) * 4096 + n0 + noff;
#pragma unroll
  for (int i = 0; i < 4; ++i) {
#pragma unroll
    for (int r = 0; r < 4; ++r) {
      const int m = i * 16 + (g4 << 2) + r;
      const float dm = dB[m];
#pragma unroll
      for (int j = 0; j < 4; ++j)
        op[(size_t)m * 4096 + (j << 4) + lm] = acc[i][j][r] * dm;
    }
  }
}

extern "C" void kernel_launch(void* const* d_in, const int* in_sizes, int n_in,
                              void* d_out, int out_size, void* d_ws, size_t ws_size,
                              hipStream_t stream) {
  const float* x    = (const float*)d_in[0];   // (8,512,64,64)
  const float* w    = (const float*)d_in[1];   // (8,512)
  const float* bw   = (const float*)d_in[2];   // (1,512,512,3,3)
  const float* modw = (const float*)d_in[3];   // (512,512)
  const float* modb = (const float*)d_in[4];   // (512,)
  float* out = (float*)d_out;                  // (8,512,64,64) fp32
  char* ws = (char*)d_ws;

  float* s_buf = (float*)(ws);                              // 16 KB
  float* d_buf = (float*)(ws + 16384);                      // 16 KB
  unsigned short* awT  = (unsigned short*)(ws + 32768);     // 4,718,592 B
  unsigned short* xpad = (unsigned short*)(ws + 4751360);   // 35,684,352 B

  (void)in_sizes; (void)n_in; (void)out_size; (void)ws_size;

  k_style<<<64,   256, 0, stream>>>(w, modw, modb, s_buf);
  k_prep <<<6176, 256, 0, stream>>>(x, s_buf, xpad);
  k_fwd  <<<512,  256, 0, stream>>>(bw, s_buf, awT, d_buf);
  k_conv <<<dim3(32, 4, 8), 256, 0, stream>>>(awT, xpad, d_buf, out);
}